// Round 21
// baseline (444.514 us; speedup 1.0000x reference)
//
#include <hip/hip_runtime.h>
#include <hip/hip_bf16.h>
#include <math.h>

#define SEQ 720
#define NCH 128
#define BATCH 128
#define BN 16384
#define DOM 72
#define PIN 30
#define POUT 30
#define FRQ 33
#define EMB 64
#define PER 24
#define KW 990
#define KP 1728
#define MT 768
#define PI_F 3.14159265358979323846f

typedef float2 cf;
typedef __attribute__((ext_vector_type(8))) short short8v;
__device__ __forceinline__ cf cmac(cf acc, cf a, cf b){
  acc.x += a.x*b.x - a.y*b.y; acc.y += a.x*b.y + a.y*b.x; return acc;
}
__device__ __forceinline__ short b2s(float f){
  __hip_bfloat16 h = __float2bfloat16(f);
  return *reinterpret_cast<short*>(&h);
}

// ---------------- P1 (1 block, 512 thr): weight composition -> C, PM, M2, o3b ----------------
__global__ __launch_bounds__(512) void p1_only(
                         const float* __restrict__ WPW, const float* __restrict__ WPb,
                         const float* __restrict__ m1r, const float* __restrict__ m1i,
                         const float* __restrict__ m1br, const float* __restrict__ m1bi,
                         const float* __restrict__ fxr, const float* __restrict__ fxi,
                         const float* __restrict__ fxbr, const float* __restrict__ fxbi,
                         const float* __restrict__ pjr, const float* __restrict__ pji,
                         const float* __restrict__ pjbr, const float* __restrict__ pjbi,
                         cf* C, cf* PM, cf* M2, cf* o3b)
{
  __shared__ double arena_d[5900];
  char* smem = (char*)arena_d;
  int tid = threadIdx.x;
  cf*    e64  = (cf*)(smem + 0);
  float* sW   = (float*)(smem + 512);
  float* sWb  = (float*)(smem + 6656);
  float* sM1r = (float*)(smem + 6912);
  float* sM1i = (float*)(smem + 10512);
  float* sFxr = (float*)(smem + 14112);
  float* sFxi = (float*)(smem + 18468);
  float* sPjr = (float*)(smem + 22824);
  float* sPji = (float*)(smem + 26424);
  float* sB   = (float*)(smem + 30024);
  cf*    s_d  = (cf*)(smem + 30816);
  cf*    s_rs = (cf*)(smem + 31080);
  cf*    s_o1 = (cf*)(smem + 31320);
  cf*    s_o2 = (cf*)(smem + 39240);
  if (tid < 64){ float s,c; sincosf(2.f*PI_F*tid/64.f, &s, &c); e64[tid] = make_float2(c, s); }
  for (int i=tid; i<EMB*PER; i+=512) sW[i]=WPW[i];
  if (tid < EMB) sWb[tid]=WPb[tid];
  for (int i=tid; i<PIN*PIN; i+=512){ sM1r[i]=m1r[i]; sM1i[i]=m1i[i]; sPjr[i]=pjr[i]; sPji[i]=pji[i]; }
  for (int i=tid; i<FRQ*FRQ; i+=512){ sFxr[i]=fxr[i]; sFxi[i]=fxi[i]; }
  if (tid < PIN)  { sB[tid]      = m1br[tid]; sB[33+tid]  = m1bi[tid]; }
  if (tid < FRQ)  { sB[66+tid]   = fxbr[tid]; sB[99+tid]  = fxbi[tid]; }
  if (tid < POUT) { sB[132+tid]  = pjbr[tid]; sB[165+tid] = pjbi[tid]; }
  __syncthreads();
  for (int idx=tid; idx<FRQ*PER; idx+=512){
    int f = idx/PER, i = idx%PER;
    cf acc = make_float2(0.f,0.f);
    #pragma unroll 8
    for (int o=0;o<EMB;++o){ cf e = e64[(f*o)&63]; float w = sW[o*PER+i]; acc.x += w*e.x; acc.y -= w*e.y; }
    C[idx] = acc;
  }
  for (int f=tid; f<FRQ; f+=512){
    cf acc = make_float2(0.f,0.f);
    #pragma unroll 8
    for (int o=0;o<EMB;++o){ cf e = e64[(f*o)&63]; acc.x += sWb[o]*e.x; acc.y -= sWb[o]*e.y; }
    s_d[f]=acc;
  }
  for (int idx=tid; idx<POUT*PIN; idx+=512){
    int q = idx/PIN, pp = idx%PIN;
    cf acc = make_float2(sPjr[q*PIN+pp], sPji[q*PIN+pp]);
    #pragma unroll 6
    for (int p=0;p<PIN;++p){
      cf a = make_float2(sPjr[q*PIN+p], sPji[q*PIN+p]);
      cf b = make_float2(sM1r[p*PIN+pp], sM1i[p*PIN+pp]);
      acc = cmac(acc, a, b);
    }
    PM[idx]=acc;
  }
  for (int idx=tid; idx<FRQ*FRQ; idx+=512){
    int f = idx/FRQ, ff = idx%FRQ;
    cf v = make_float2(sFxr[idx], sFxi[idx]); if (f==ff) v.x += 1.f;
    M2[idx]=v;
  }
  for (int p=tid; p<PIN; p+=512){
    cf acc = make_float2(1.f,0.f);
    #pragma unroll 6
    for (int pp=0;pp<PIN;++pp){ acc.x += sM1r[p*PIN+pp]; acc.y += sM1i[p*PIN+pp]; }
    s_rs[p]=acc;
  }
  __syncthreads();
  for (int idx=tid; idx<FRQ*PIN; idx+=512){
    int f = idx/PIN, p = idx%PIN;
    cf v = make_float2(0.f,0.f); v = cmac(v, s_d[f], s_rs[p]);
    v.x += sB[p]; v.y += sB[33+p];
    s_o1[idx]=v;
  }
  __syncthreads();
  for (int idx=tid; idx<FRQ*PIN; idx+=512){
    int f = idx/PIN, p = idx%PIN;
    cf acc = make_float2(sB[66+f], sB[99+f]);
    #pragma unroll 4
    for (int ff=0; ff<FRQ; ++ff){
      cf m2 = make_float2(sFxr[f*FRQ+ff], sFxi[f*FRQ+ff]); if (f==ff) m2.x += 1.f;
      acc = cmac(acc, m2, s_o1[ff*PIN+p]);
    }
    s_o2[idx]=acc;
  }
  __syncthreads();
  for (int idx=tid; idx<FRQ*POUT; idx+=512){
    int f = idx/POUT, q = idx%POUT;
    cf acc = make_float2(sB[132+q], sB[165+q]);
    #pragma unroll 6
    for (int p=0;p<PIN;++p){
      cf a = make_float2(sPjr[q*PIN+p], sPji[q*PIN+p]);
      acc = cmac(acc, a, s_o2[f*PIN+p]);
    }
    o3b[f*POUT+q]=acc;
  }
}

// ---------------- MEGA (512 thr, 5840 blocks): p_big4 striped 1-in-8 among repack blocks.
// p_big4: p2+p3+p4+p7 + gw-fold Mlow (NO A1 dependency) + BTm + bias.
// repack: x transpose / Wpos. ----------------
__global__ __launch_bounds__(512) void mega(const float* __restrict__ hW,
                    const cf* __restrict__ PM, const cf* __restrict__ M2, const cf* __restrict__ o3b,
                    const cf* __restrict__ Cm,
                    const float* __restrict__ fqr, const float* __restrict__ fqi,
                    const float* __restrict__ fbr, const float* __restrict__ fbi,
                    const float* __restrict__ headb,
                    const float* __restrict__ x, const float* __restrict__ Wp,
                    __hip_bfloat16* __restrict__ BTm, float* __restrict__ bias,
                    __hip_bfloat16* __restrict__ Abig){
  __shared__ double smem_d[6336];   // 50688 B arena
  char* smem = (char*)smem_d;
  int tid = threadIdx.x;
  int blk = blockIdx.x;

  bool isP4 = ((blk & 7) == 0) && (blk < 5760);
  if (isP4){
    // ---------- p_big4 ----------
    cf*    e64 = (cf*)(smem + 0);
    float* shw = (float*)(smem + 512);
    cf*    sHc = (cf*)(smem + 8192);
    cf*    sV1 = (cf*)(smem + 16112);
    cf*    sPM = (cf*)(smem + 24032);    // dead after phase B -> reused as tbl in D/E
    cf*    sM2 = (cf*)(smem + 31232);
    cf*    sO3 = (cf*)(smem + 39944);
    float* red = (float*)(smem + 47864);
    cf*    gw  = (cf*)(smem + 49912);    // 72 cf = 576 B (old sG slot)
    cf* sC = (cf*)shw;                   // aliases shw after phase A
    cf* sV = sHc;                        // aliases sHc after phase B
    cf* tbl = sPM;                       // aliases sPM after phase B (720 cf = 5760 <= 7200)
    int t = blk >> 3;
    if (tid<64){ float s,c; sincosf(2.f*PI_F*tid/64.f,&s,&c); e64[tid]=make_float2(c,s); }
    for (int i=tid;i<1920;i+=512) shw[i]=hW[(size_t)t*1920+i];
    for (int i=tid;i<POUT*PIN;i+=512) sPM[i]=PM[i];
    for (int i=tid;i<FRQ*FRQ;i+=512) sM2[i]=M2[i];
    for (int i=tid;i<FRQ*POUT;i+=512) sO3[i]=o3b[i];
    // gw[j] = sum_k Ghat[t,k]*Wfreq[k,j]  (complex; Ghat = sc_k * e^{+2pi i k t/720})
    if (tid < DOM){
      int j = tid;
      cf acc = make_float2(0.f,0.f);
      for (int k=0;k<DOM;++k){
        int m=(k*t)%720; float s,c; sincosf(2.f*PI_F*(float)m/720.f,&s,&c);
        float sc=(k==0)?(1.f/720.f):(2.f/720.f);
        float wr = fqr[k*DOM+j], wi = fqi[k*DOM+j];
        acc.x += sc*(c*wr - s*wi);
        acc.y += sc*(c*wi + s*wr);
      }
      gw[j] = acc;
    }
    __syncthreads();
    // A: Hc[q][f]
    for (int idx=tid; idx<990; idx+=512){
      int q=idx/FRQ, f=idx%FRQ;
      cf acc=make_float2(0.f,0.f);
      const float* hw = &shw[q*64];
      #pragma unroll 8
      for (int o=0;o<EMB;++o){ cf e=e64[(f*o)&63]; float w=hw[o]; acc.x+=w*e.x; acc.y+=w*e.y; }
      float s=((f==0)||(f==32))?(1.f/64.f):(2.f/64.f);
      sHc[idx]=make_float2(acc.x*s, acc.y*s);
    }
    __syncthreads();   // shw consumed; sHc ready
    // B: V1 ; bias partial ; load sC (overwrites shw)
    for (int idx=tid; idx<990; idx+=512){
      int f=idx/PIN, p=idx%PIN;
      cf acc=make_float2(0.f,0.f);
      #pragma unroll 6
      for (int q=0;q<POUT;++q) acc=cmac(acc, sHc[q*FRQ+f], sPM[q*PIN+p]);
      sV1[idx]=acc;
    }
    float part=0.f;
    for (int idx=tid; idx<990; idx+=512){
      int q=idx/FRQ, f=idx%FRQ;
      cf h=sHc[idx]; cf o=sO3[f*POUT+q];
      part += h.x*o.x - h.y*o.y;
    }
    part *= 0.7f;
    if (tid<DOM){
      int m=(tid*t)%720; float s,c; sincosf(2.f*PI_F*(float)m/720.f,&s,&c);
      float sc=(tid==0)?(1.f/720.f):(2.f/720.f);
      part += 0.3f*sc*(c*fbr[tid] - s*fbi[tid]);
    }
    for (int i=tid;i<FRQ*PER;i+=512) sC[i]=Cm[i];
    red[tid]=part; __syncthreads();
    for (int s=256;s>0;s>>=1){ if (tid<s) red[tid]+=red[tid+s]; __syncthreads(); }
    if (tid==0) bias[t] = red[0] + 0.7f*headb[t];
    __syncthreads();   // sHc & sPM reads done; sC loaded
    // D: V[ff][pp] -> sV ; fill tbl (into dead sPM region)
    for (int idx=tid; idx<990; idx+=512){
      int ff=idx/PIN, pp=idx%PIN;
      cf acc=make_float2(0.f,0.f);
      #pragma unroll 4
      for (int f=0;f<FRQ;++f) acc=cmac(acc, sV1[f*PIN+pp], sM2[f*FRQ+ff]);
      sV[idx]=acc;
    }
    for (int m=tid;m<720;m+=512){
      float s,c; sincosf(2.f*PI_F*(float)m/720.f,&s,&c);
      tbl[m]=make_float2(c,s);
    }
    __syncthreads();
    // E: mper + Mlow(gw-fold) -> BTm[:,0:720] ; Wpos columns -> BTm[:,720:1728)
    for (int tau=tid; tau<720; tau+=512){
      int p0 = tau/PER, i0 = tau - p0*PER;
      float mper=0.f;
      #pragma unroll 4
      for (int f=0; f<FRQ; ++f){ cf v=sV[f*PIN+p0]; cf c=sC[f*PER+i0]; mper += v.x*c.x - v.y*c.y; }
      float mlow=0.f;
      #pragma unroll 8
      for (int j=0;j<DOM;++j){
        cf g = gw[j]; cf e = tbl[(j*tau)%720];
        mlow += g.x*e.x + g.y*e.y;     // Re(gw * e^{-i theta})
      }
      BTm[(size_t)t*KP + tau] = __float2bfloat16(0.3f*mlow + 0.7f*mper);
    }
    for (int j=tid;j<KP-SEQ;j+=512){
      float v = 0.f;
      if (j < KW){ int p=j/FRQ, f=j-p*FRQ; v = 0.7f * sV[f*PIN+p].x; }
      BTm[(size_t)t*KP + SEQ + j] = __float2bfloat16(v);
    }
    return;
  }

  // repack id
  int rid = (blk < 5760) ? (blk - (blk>>3) - 1) : (blk - 720);

  if (rid < 3072){
    // ---- x transpose: 64x64 tile, float4 loads, short8 stores ----
    float (*tile)[68] = (float(*)[68])smem;
    int b = rid/24; int rem = rid%24;
    int t0 = (rem>>1)*64, n0 = (rem&1)*64;
    int r0 = tid >> 4;
    int c4 = (tid & 15)*4;
    #pragma unroll
    for (int s=0;s<2;++s){
      int r = r0 + s*32;
      int t = t0 + r;
      float4 v = make_float4(0.f,0.f,0.f,0.f);
      if (t < SEQ) v = *reinterpret_cast<const float4*>(&x[((size_t)b*SEQ + t)*NCH + n0 + c4]);
      *reinterpret_cast<float4*>(&tile[r][c4]) = v;
    }
    __syncthreads();
    int n  = tid & 63;
    int tg = tid >> 6;
    int tt = tg*8;
    if (t0 + tt < SEQ){
      short8v v;
      #pragma unroll
      for (int j=0;j<8;++j) v[j] = b2s(tile[tt+j][n]);
      *reinterpret_cast<short8v*>(Abig + (size_t)(b*NCH + n0+n)*KP + t0 + tt) = v;
    }
    return;
  }

  // ---- Wpos repack: 8 bn per block ----
  {
    int bb = rid - 3072;
    int lane8 = tid >> 6;
    int bn = bb*8 + lane8;
    int j = (tid & 63)*4;
    const float* src = Wp + (size_t)bn*KW;
    __hip_bfloat16* dstb = Abig + (size_t)bn*KP + SEQ;
    for (int jj = j; jj < KP-SEQ; jj += 256){
      float f0,f1,f2,f3;
      if (jj+3 < KW){
        float2 u = *reinterpret_cast<const float2*>(src+jj);
        float2 w = *reinterpret_cast<const float2*>(src+jj+2);
        f0=u.x; f1=u.y; f2=w.x; f3=w.y;
      } else {
        f0=(jj  <KW)?src[jj  ]:0.f; f1=(jj+1<KW)?src[jj+1]:0.f;
        f2=(jj+2<KW)?src[jj+2]:0.f; f3=(jj+3<KW)?src[jj+3]:0.f;
      }
      short4 v = { b2s(f0), b2s(f1), b2s(f2), b2s(f3) };
      *reinterpret_cast<short4*>(dstb + jj) = v;
    }
  }
}

// ---------------- GEMM: 1-phase, 512 threads / 8 waves (proven r20: 64.5us, MfmaUtil 27.5) ----------------
typedef __attribute__((ext_vector_type(8))) short bfrag_t;
typedef __attribute__((ext_vector_type(4))) float accf_t;
typedef __attribute__((address_space(1))) void gvoid;
typedef __attribute__((address_space(3))) void lvoid;

__device__ __forceinline__ void gload16(const void* g, void* l){
  __builtin_amdgcn_global_load_lds((gvoid*)(g), (lvoid*)(l), 16, 0, 0);
}

__global__ __launch_bounds__(512, 6) void gemm_main(const __hip_bfloat16* __restrict__ BTm,
                                                    const __hip_bfloat16* __restrict__ Abig,
                                                    const float* __restrict__ bias,
                                                    float* __restrict__ out)
{
  __shared__ __hip_bfloat16 At[128*32];
  __shared__ __hip_bfloat16 Bt[128*32];
  int tid = threadIdx.x;
  int lane = tid & 63;
  int wv = tid >> 6;
  int wr = wv >> 1, wc = wv & 1;
  int t0 = blockIdx.y*128, bn0 = blockIdx.x*128;

  accf_t acc[2][4];
  #pragma unroll
  for (int i=0;i<2;++i)
    #pragma unroll
    for (int j=0;j<4;++j) acc[i][j] = (accf_t){0.f,0.f,0.f,0.f};

  int row = tid >> 2, u = tid & 3;
  int ug = u ^ ((row>>1)&3);
  const __hip_bfloat16* gA = BTm  + (size_t)(t0 + row)*KP + ug*8;
  const __hip_bfloat16* gB = Abig + (size_t)(bn0+ row)*KP + ug*8;
  char* lA = (char*)At + tid*16;
  char* lB = (char*)Bt + tid*16;

  int g = lane>>4;
  int arowb = wr*32 + (lane&15);
  int browb = wc*64 + (lane&15);

  for (int ks=0; ks<KP/32; ++ks){
    int k0 = ks*32;
    gload16(gA + k0, lA);
    gload16(gB + k0, lB);
    __syncthreads();
    bfrag_t af[2], bb[4];
    #pragma unroll
    for (int mi=0;mi<2;++mi){
      int r = arowb + mi*16;
      int uu = g ^ ((r>>1)&3);
      af[mi] = *(const bfrag_t*)((const char*)At + r*64 + uu*16);
    }
    #pragma unroll
    for (int ni=0;ni<4;++ni){
      int r = browb + ni*16;
      int uu = g ^ ((r>>1)&3);
      bb[ni] = *(const bfrag_t*)((const char*)Bt + r*64 + uu*16);
    }
    #pragma unroll
    for (int mi=0;mi<2;++mi)
      #pragma unroll
      for (int ni=0;ni<4;++ni)
        acc[mi][ni] = __builtin_amdgcn_mfma_f32_16x16x32_bf16(af[mi], bb[ni], acc[mi][ni], 0, 0, 0);
    __syncthreads();
  }

  #pragma unroll
  for (int mi=0;mi<2;++mi){
    int tbase = t0 + wr*32 + mi*16 + (lane>>4)*4;
    #pragma unroll
    for (int ni=0;ni<4;++ni){
      int col = bn0 + wc*64 + ni*16 + (lane&15);
      int b = col>>7, n = col&127;
      size_t obase = (size_t)b*(SEQ*NCH) + n;
      #pragma unroll
      for (int r=0;r<4;++r){
        int t = tbase + r;
        if (t<SEQ) out[obase + (size_t)t*NCH] = acc[mi][ni][r] + bias[t];
      }
    }
  }
}

extern "C" void kernel_launch(void* const* d_in, const int* in_sizes, int n_in,
                              void* d_out, int out_size, void* d_ws, size_t ws_size,
                              hipStream_t stream)
{
  const float* x     = (const float*)d_in[0];
  const float* fqWr  = (const float*)d_in[1];
  const float* fqWi  = (const float*)d_in[2];
  const float* fqbr  = (const float*)d_in[3];
  const float* fqbi  = (const float*)d_in[4];
  const float* WPW   = (const float*)d_in[5];
  const float* WPb   = (const float*)d_in[6];
  const float* Wpos  = (const float*)d_in[7];
  const float* m1r   = (const float*)d_in[8];
  const float* m1i   = (const float*)d_in[9];
  const float* m1br  = (const float*)d_in[10];
  const float* m1bi  = (const float*)d_in[11];
  const float* fxr   = (const float*)d_in[12];
  const float* fxi   = (const float*)d_in[13];
  const float* fxbr  = (const float*)d_in[14];
  const float* fxbi  = (const float*)d_in[15];
  const float* pjr   = (const float*)d_in[16];
  const float* pji   = (const float*)d_in[17];
  const float* pjbr  = (const float*)d_in[18];
  const float* pjbi  = (const float*)d_in[19];
  const float* headW = (const float*)d_in[20];
  const float* headb = (const float*)d_in[21];

  char* ws = (char*)d_ws;
  size_t off = 0;
  auto alloc = [&](size_t bytes)->void*{ void* p = ws + off; off += (bytes + 255) & ~(size_t)255; return p; };
  __hip_bfloat16* Abig = (__hip_bfloat16*)alloc((size_t)BN*KP*2);
  __hip_bfloat16* BTm  = (__hip_bfloat16*)alloc((size_t)MT*KP*2);
  cf* C   = (cf*)alloc((size_t)FRQ*PER*8);
  cf* PM  = (cf*)alloc((size_t)POUT*PIN*8);
  cf* M2  = (cf*)alloc((size_t)FRQ*FRQ*8);
  cf* o3b = (cf*)alloc((size_t)FRQ*POUT*8);
  float* bias = (float*)alloc((size_t)SEQ*4);

  p1_only<<<1,512,0,stream>>>(WPW,WPb, m1r,m1i,m1br,m1bi, fxr,fxi,fxbr,fxbi,
                              pjr,pji,pjbr,pjbi, C,PM,M2,o3b);
  mega<<<5840,512,0,stream>>>(headW, PM, M2, o3b, C, fqWr, fqWi, fqbr, fqbi, headb,
                              x, Wpos, BTm, bias, Abig);
  gemm_main<<<dim3(128, 6), 512, 0, stream>>>(BTm, Abig, bias, (float*)d_out);
}

// Round 22
// 126.125 us; speedup vs baseline: 3.5244x; 3.5244x over previous
//
#include <hip/hip_runtime.h>
#include <hip/hip_bf16.h>
#include <math.h>

#define SEQ 720
#define NCH 128
#define BATCH 128
#define BN 16384
#define DOM 72
#define PIN 30
#define POUT 30
#define FRQ 33
#define EMB 64
#define PER 24
#define KW 990
#define KP 1728
#define MT 768
#define PI_F 3.14159265358979323846f

typedef float2 cf;
typedef __attribute__((ext_vector_type(8))) short short8v;
__device__ __forceinline__ cf cmac(cf acc, cf a, cf b){
  acc.x += a.x*b.x - a.y*b.y; acc.y += a.x*b.y + a.y*b.x; return acc;
}
__device__ __forceinline__ short b2s(float f){
  __hip_bfloat16 h = __float2bfloat16(f);
  return *reinterpret_cast<short*>(&h);
}

// ---------------- FUSED_PRE (512 thr): blk[0,72)=A1 rows ; blk 72=p1 ; blk[73,3145)=x transpose
//                  (float4 load / short8 store) ; blk[3145,5193)=Wpos repack ----------------
__global__ __launch_bounds__(512) void fused_pre(
                         const float* __restrict__ WPW, const float* __restrict__ WPb,
                         const float* __restrict__ m1r, const float* __restrict__ m1i,
                         const float* __restrict__ m1br, const float* __restrict__ m1bi,
                         const float* __restrict__ fxr, const float* __restrict__ fxi,
                         const float* __restrict__ fxbr, const float* __restrict__ fxbi,
                         const float* __restrict__ pjr, const float* __restrict__ pji,
                         const float* __restrict__ pjbr, const float* __restrict__ pjbi,
                         const float* __restrict__ fqr, const float* __restrict__ fqi,
                         const float* __restrict__ x, const float* __restrict__ Wp,
                         cf* C, cf* PM, cf* M2, cf* o3b,
                         float* __restrict__ A1r, float* __restrict__ A1i,
                         __hip_bfloat16* __restrict__ Abig)
{
  __shared__ double arena_d[5900];   // 47200 B
  char* smem = (char*)arena_d;
  int tid = threadIdx.x;
  int blk = blockIdx.x;

  if (blk < DOM){
    cf* tbl  = (cf*)(smem);
    cf* wrow = (cf*)(smem + 5760);
    int k = blk;
    for (int m=tid;m<720;m+=512){ float s,c; sincosf(-2.f*PI_F*(float)m/720.f,&s,&c); tbl[m]=make_float2(c,s); }
    for (int j=tid;j<DOM;j+=512) wrow[j]=make_float2(fqr[k*DOM+j], fqi[k*DOM+j]);
    __syncthreads();
    for (int tau=tid; tau<720; tau+=512){
      cf acc=make_float2(0.f,0.f);
      for (int j=0;j<DOM;++j) acc = cmac(acc, wrow[j], tbl[(j*tau)%720]);
      A1r[k*720+tau]=acc.x;
      A1i[k*720+tau]=acc.y;
    }
    return;
  }

  if (blk == DOM){
    cf*    e64  = (cf*)(smem + 0);
    float* sW   = (float*)(smem + 512);
    float* sWb  = (float*)(smem + 6656);
    float* sM1r = (float*)(smem + 6912);
    float* sM1i = (float*)(smem + 10512);
    float* sFxr = (float*)(smem + 14112);
    float* sFxi = (float*)(smem + 18468);
    float* sPjr = (float*)(smem + 22824);
    float* sPji = (float*)(smem + 26424);
    float* sB   = (float*)(smem + 30024);
    cf*    s_d  = (cf*)(smem + 30816);
    cf*    s_rs = (cf*)(smem + 31080);
    cf*    s_o1 = (cf*)(smem + 31320);
    cf*    s_o2 = (cf*)(smem + 39240);
    if (tid < 64){ float s,c; sincosf(2.f*PI_F*tid/64.f, &s, &c); e64[tid] = make_float2(c, s); }
    for (int i=tid; i<EMB*PER; i+=512) sW[i]=WPW[i];
    if (tid < EMB) sWb[tid]=WPb[tid];
    for (int i=tid; i<PIN*PIN; i+=512){ sM1r[i]=m1r[i]; sM1i[i]=m1i[i]; sPjr[i]=pjr[i]; sPji[i]=pji[i]; }
    for (int i=tid; i<FRQ*FRQ; i+=512){ sFxr[i]=fxr[i]; sFxi[i]=fxi[i]; }
    if (tid < PIN)  { sB[tid]      = m1br[tid]; sB[33+tid]  = m1bi[tid]; }
    if (tid < FRQ)  { sB[66+tid]   = fxbr[tid]; sB[99+tid]  = fxbi[tid]; }
    if (tid < POUT) { sB[132+tid]  = pjbr[tid]; sB[165+tid] = pjbi[tid]; }
    __syncthreads();
    for (int idx=tid; idx<FRQ*PER; idx+=512){
      int f = idx/PER, i = idx%PER;
      cf acc = make_float2(0.f,0.f);
      #pragma unroll 8
      for (int o=0;o<EMB;++o){ cf e = e64[(f*o)&63]; float w = sW[o*PER+i]; acc.x += w*e.x; acc.y -= w*e.y; }
      C[idx] = acc;
    }
    for (int f=tid; f<FRQ; f+=512){
      cf acc = make_float2(0.f,0.f);
      #pragma unroll 8
      for (int o=0;o<EMB;++o){ cf e = e64[(f*o)&63]; acc.x += sWb[o]*e.x; acc.y -= sWb[o]*e.y; }
      s_d[f]=acc;
    }
    for (int idx=tid; idx<POUT*PIN; idx+=512){
      int q = idx/PIN, pp = idx%PIN;
      cf acc = make_float2(sPjr[q*PIN+pp], sPji[q*PIN+pp]);
      #pragma unroll 6
      for (int p=0;p<PIN;++p){
        cf a = make_float2(sPjr[q*PIN+p], sPji[q*PIN+p]);
        cf b = make_float2(sM1r[p*PIN+pp], sM1i[p*PIN+pp]);
        acc = cmac(acc, a, b);
      }
      PM[idx]=acc;
    }
    for (int idx=tid; idx<FRQ*FRQ; idx+=512){
      int f = idx/FRQ, ff = idx%FRQ;
      cf v = make_float2(sFxr[idx], sFxi[idx]); if (f==ff) v.x += 1.f;
      M2[idx]=v;
    }
    for (int p=tid; p<PIN; p+=512){
      cf acc = make_float2(1.f,0.f);
      #pragma unroll 6
      for (int pp=0;pp<PIN;++pp){ acc.x += sM1r[p*PIN+pp]; acc.y += sM1i[p*PIN+pp]; }
      s_rs[p]=acc;
    }
    __syncthreads();
    for (int idx=tid; idx<FRQ*PIN; idx+=512){
      int f = idx/PIN, p = idx%PIN;
      cf v = make_float2(0.f,0.f); v = cmac(v, s_d[f], s_rs[p]);
      v.x += sB[p]; v.y += sB[33+p];
      s_o1[idx]=v;
    }
    __syncthreads();
    for (int idx=tid; idx<FRQ*PIN; idx+=512){
      int f = idx/PIN, p = idx%PIN;
      cf acc = make_float2(sB[66+f], sB[99+f]);
      #pragma unroll 4
      for (int ff=0; ff<FRQ; ++ff){
        cf m2 = make_float2(sFxr[f*FRQ+ff], sFxi[f*FRQ+ff]); if (f==ff) m2.x += 1.f;
        acc = cmac(acc, m2, s_o1[ff*PIN+p]);
      }
      s_o2[idx]=acc;
    }
    __syncthreads();
    for (int idx=tid; idx<FRQ*POUT; idx+=512){
      int f = idx/POUT, q = idx%POUT;
      cf acc = make_float2(sB[132+q], sB[165+q]);
      #pragma unroll 6
      for (int p=0;p<PIN;++p){
        cf a = make_float2(sPjr[q*PIN+p], sPji[q*PIN+p]);
        acc = cmac(acc, a, s_o2[f*PIN+p]);
      }
      o3b[f*POUT+q]=acc;
    }
    return;
  }

  if (blk < DOM + 1 + 3072){
    float (*tile)[68] = (float(*)[68])smem;
    int bb = blk - (DOM+1);
    int b = bb/24; int rem = bb%24;
    int t0 = (rem>>1)*64, n0 = (rem&1)*64;
    int r0 = tid >> 4;
    int c4 = (tid & 15)*4;
    #pragma unroll
    for (int s=0;s<2;++s){
      int r = r0 + s*32;
      int t = t0 + r;
      float4 v = make_float4(0.f,0.f,0.f,0.f);
      if (t < SEQ) v = *reinterpret_cast<const float4*>(&x[((size_t)b*SEQ + t)*NCH + n0 + c4]);
      *reinterpret_cast<float4*>(&tile[r][c4]) = v;
    }
    __syncthreads();
    int n  = tid & 63;
    int tg = tid >> 6;
    int tt = tg*8;
    if (t0 + tt < SEQ){
      short8v v;
      #pragma unroll
      for (int j=0;j<8;++j) v[j] = b2s(tile[tt+j][n]);
      *reinterpret_cast<short8v*>(Abig + (size_t)(b*NCH + n0+n)*KP + t0 + tt) = v;
    }
    return;
  }

  {
    int bb = blk - (DOM+1) - 3072;
    int lane8 = tid >> 6;
    int bn = bb*8 + lane8;
    int j = (tid & 63)*4;
    const float* src = Wp + (size_t)bn*KW;
    __hip_bfloat16* dstb = Abig + (size_t)bn*KP + SEQ;
    for (int jj = j; jj < KP-SEQ; jj += 256){
      float f0,f1,f2,f3;
      if (jj+3 < KW){
        float2 u = *reinterpret_cast<const float2*>(src+jj);
        float2 w = *reinterpret_cast<const float2*>(src+jj+2);
        f0=u.x; f1=u.y; f2=w.x; f3=w.y;
      } else {
        f0=(jj  <KW)?src[jj  ]:0.f; f1=(jj+1<KW)?src[jj+1]:0.f;
        f2=(jj+2<KW)?src[jj+2]:0.f; f3=(jj+3<KW)?src[jj+3]:0.f;
      }
      short4 v = { b2s(f0), b2s(f1), b2s(f2), b2s(f3) };
      *reinterpret_cast<short4*>(dstb + jj) = v;
    }
  }
}

// ---------------- P_BIG3 (512 thr, 720 blocks — all co-resident in ONE batch) ----------------
__global__ __launch_bounds__(512) void p_big3(const float* __restrict__ hW,
                    const cf* __restrict__ PM, const cf* __restrict__ M2, const cf* __restrict__ o3b,
                    const cf* __restrict__ Cm,
                    const float* __restrict__ fbr, const float* __restrict__ fbi,
                    const float* __restrict__ headb,
                    const float* __restrict__ A1r, const float* __restrict__ A1i,
                    __hip_bfloat16* __restrict__ BTm, float* __restrict__ bias){
  __shared__ double smem_d[6336];
  char* smem = (char*)smem_d;
  int tid = threadIdx.x;
  cf*    e64 = (cf*)(smem + 0);
  float* shw = (float*)(smem + 512);
  cf*    sHc = (cf*)(smem + 8192);
  cf*    sV1 = (cf*)(smem + 16112);
  cf*    sPM = (cf*)(smem + 24032);
  cf*    sM2 = (cf*)(smem + 31232);
  cf*    sO3 = (cf*)(smem + 39944);
  float* red = (float*)(smem + 47864);
  float* sG  = (float*)(smem + 49912);
  cf* sC = (cf*)shw;
  cf* sV = sHc;
  int t = blockIdx.x;
  if (tid<64){ float s,c; sincosf(2.f*PI_F*tid/64.f,&s,&c); e64[tid]=make_float2(c,s); }
  if (tid<DOM){
    int m=(tid*t)%720; float s,c; sincosf(2.f*PI_F*(float)m/720.f,&s,&c);
    float sc=(tid==0)?(1.f/720.f):(2.f/720.f);
    sG[tid]=c*sc; sG[72+tid]=s*sc;
  }
  for (int i=tid;i<1920;i+=512) shw[i]=hW[(size_t)t*1920+i];
  for (int i=tid;i<POUT*PIN;i+=512) sPM[i]=PM[i];
  for (int i=tid;i<FRQ*FRQ;i+=512) sM2[i]=M2[i];
  for (int i=tid;i<FRQ*POUT;i+=512) sO3[i]=o3b[i];
  __syncthreads();
  for (int idx=tid; idx<990; idx+=512){
    int q=idx/FRQ, f=idx%FRQ;
    cf acc=make_float2(0.f,0.f);
    const float* hw = &shw[q*64];
    #pragma unroll 8
    for (int o=0;o<EMB;++o){ cf e=e64[(f*o)&63]; float w=hw[o]; acc.x+=w*e.x; acc.y+=w*e.y; }
    float s=((f==0)||(f==32))?(1.f/64.f):(2.f/64.f);
    sHc[idx]=make_float2(acc.x*s, acc.y*s);
  }
  __syncthreads();
  for (int idx=tid; idx<990; idx+=512){
    int f=idx/PIN, p=idx%PIN;
    cf acc=make_float2(0.f,0.f);
    #pragma unroll 6
    for (int q=0;q<POUT;++q) acc=cmac(acc, sHc[q*FRQ+f], sPM[q*PIN+p]);
    sV1[idx]=acc;
  }
  float part=0.f;
  for (int idx=tid; idx<990; idx+=512){
    int q=idx/FRQ, f=idx%FRQ;
    cf h=sHc[idx]; cf o=sO3[f*POUT+q];
    part += h.x*o.x - h.y*o.y;
  }
  part *= 0.7f;
  if (tid<DOM){
    int m=(tid*t)%720; float s,c; sincosf(2.f*PI_F*(float)m/720.f,&s,&c);
    float sc=(tid==0)?(1.f/720.f):(2.f/720.f);
    part += 0.3f*sc*(c*fbr[tid] - s*fbi[tid]);
  }
  for (int i=tid;i<FRQ*PER;i+=512) sC[i]=Cm[i];
  red[tid]=part; __syncthreads();
  for (int s=256;s>0;s>>=1){ if (tid<s) red[tid]+=red[tid+s]; __syncthreads(); }
  if (tid==0) bias[t] = red[0] + 0.7f*headb[t];
  __syncthreads();
  for (int idx=tid; idx<990; idx+=512){
    int ff=idx/PIN, pp=idx%PIN;
    cf acc=make_float2(0.f,0.f);
    #pragma unroll 4
    for (int f=0;f<FRQ;++f) acc=cmac(acc, sV1[f*PIN+pp], sM2[f*FRQ+ff]);
    sV[idx]=acc;
  }
  __syncthreads();
  for (int tau=tid; tau<720; tau+=512){
    int p0 = tau/PER, i0 = tau - p0*PER;
    float mper=0.f;
    #pragma unroll 4
    for (int f=0; f<FRQ; ++f){ cf v=sV[f*PIN+p0]; cf c=sC[f*PER+i0]; mper += v.x*c.x - v.y*c.y; }
    float mlow=0.f;
    #pragma unroll 8
    for (int k=0;k<DOM;++k)
      mlow += sG[k]*A1r[k*720+tau] - sG[72+k]*A1i[k*720+tau];
    BTm[(size_t)t*KP + tau] = __float2bfloat16(0.3f*mlow + 0.7f*mper);
  }
  for (int j=tid;j<KP-SEQ;j+=512){
    float v = 0.f;
    if (j < KW){ int p=j/FRQ, f=j-p*FRQ; v = 0.7f * sV[f*PIN+p].x; }
    BTm[(size_t)t*KP + SEQ + j] = __float2bfloat16(v);
  }
}

// ---------------- GEMM: 1-phase, 512 threads / 8 waves (proven r20: 64.5us, MfmaUtil 27.5) ----------------
typedef __attribute__((ext_vector_type(8))) short bfrag_t;
typedef __attribute__((ext_vector_type(4))) float accf_t;
typedef __attribute__((address_space(1))) void gvoid;
typedef __attribute__((address_space(3))) void lvoid;

__device__ __forceinline__ void gload16(const void* g, void* l){
  __builtin_amdgcn_global_load_lds((gvoid*)(g), (lvoid*)(l), 16, 0, 0);
}

__global__ __launch_bounds__(512, 6) void gemm_main(const __hip_bfloat16* __restrict__ BTm,
                                                    const __hip_bfloat16* __restrict__ Abig,
                                                    const float* __restrict__ bias,
                                                    float* __restrict__ out)
{
  __shared__ __hip_bfloat16 At[128*32];
  __shared__ __hip_bfloat16 Bt[128*32];
  int tid = threadIdx.x;
  int lane = tid & 63;
  int wv = tid >> 6;
  int wr = wv >> 1, wc = wv & 1;
  int t0 = blockIdx.y*128, bn0 = blockIdx.x*128;

  accf_t acc[2][4];
  #pragma unroll
  for (int i=0;i<2;++i)
    #pragma unroll
    for (int j=0;j<4;++j) acc[i][j] = (accf_t){0.f,0.f,0.f,0.f};

  int row = tid >> 2, u = tid & 3;
  int ug = u ^ ((row>>1)&3);
  const __hip_bfloat16* gA = BTm  + (size_t)(t0 + row)*KP + ug*8;
  const __hip_bfloat16* gB = Abig + (size_t)(bn0+ row)*KP + ug*8;
  char* lA = (char*)At + tid*16;
  char* lB = (char*)Bt + tid*16;

  int g = lane>>4;
  int arowb = wr*32 + (lane&15);
  int browb = wc*64 + (lane&15);

  for (int ks=0; ks<KP/32; ++ks){
    int k0 = ks*32;
    gload16(gA + k0, lA);
    gload16(gB + k0, lB);
    __syncthreads();
    bfrag_t af[2], bb[4];
    #pragma unroll
    for (int mi=0;mi<2;++mi){
      int r = arowb + mi*16;
      int uu = g ^ ((r>>1)&3);
      af[mi] = *(const bfrag_t*)((const char*)At + r*64 + uu*16);
    }
    #pragma unroll
    for (int ni=0;ni<4;++ni){
      int r = browb + ni*16;
      int uu = g ^ ((r>>1)&3);
      bb[ni] = *(const bfrag_t*)((const char*)Bt + r*64 + uu*16);
    }
    #pragma unroll
    for (int mi=0;mi<2;++mi)
      #pragma unroll
      for (int ni=0;ni<4;++ni)
        acc[mi][ni] = __builtin_amdgcn_mfma_f32_16x16x32_bf16(af[mi], bb[ni], acc[mi][ni], 0, 0, 0);
    __syncthreads();
  }

  #pragma unroll
  for (int mi=0;mi<2;++mi){
    int tbase = t0 + wr*32 + mi*16 + (lane>>4)*4;
    #pragma unroll
    for (int ni=0;ni<4;++ni){
      int col = bn0 + wc*64 + ni*16 + (lane&15);
      int b = col>>7, n = col&127;
      size_t obase = (size_t)b*(SEQ*NCH) + n;
      #pragma unroll
      for (int r=0;r<4;++r){
        int t = tbase + r;
        if (t<SEQ) out[obase + (size_t)t*NCH] = acc[mi][ni][r] + bias[t];
      }
    }
  }
}

extern "C" void kernel_launch(void* const* d_in, const int* in_sizes, int n_in,
                              void* d_out, int out_size, void* d_ws, size_t ws_size,
                              hipStream_t stream)
{
  const float* x     = (const float*)d_in[0];
  const float* fqWr  = (const float*)d_in[1];
  const float* fqWi  = (const float*)d_in[2];
  const float* fqbr  = (const float*)d_in[3];
  const float* fqbi  = (const float*)d_in[4];
  const float* WPW   = (const float*)d_in[5];
  const float* WPb   = (const float*)d_in[6];
  const float* Wpos  = (const float*)d_in[7];
  const float* m1r   = (const float*)d_in[8];
  const float* m1i   = (const float*)d_in[9];
  const float* m1br  = (const float*)d_in[10];
  const float* m1bi  = (const float*)d_in[11];
  const float* fxr   = (const float*)d_in[12];
  const float* fxi   = (const float*)d_in[13];
  const float* fxbr  = (const float*)d_in[14];
  const float* fxbi  = (const float*)d_in[15];
  const float* pjr   = (const float*)d_in[16];
  const float* pji   = (const float*)d_in[17];
  const float* pjbr  = (const float*)d_in[18];
  const float* pjbi  = (const float*)d_in[19];
  const float* headW = (const float*)d_in[20];
  const float* headb = (const float*)d_in[21];

  char* ws = (char*)d_ws;
  size_t off = 0;
  auto alloc = [&](size_t bytes)->void*{ void* p = ws + off; off += (bytes + 255) & ~(size_t)255; return p; };
  __hip_bfloat16* Abig = (__hip_bfloat16*)alloc((size_t)BN*KP*2);
  __hip_bfloat16* BTm  = (__hip_bfloat16*)alloc((size_t)MT*KP*2);
  float* A1r = (float*)alloc((size_t)DOM*720*4);
  float* A1i = (float*)alloc((size_t)DOM*720*4);
  cf* C   = (cf*)alloc((size_t)FRQ*PER*8);
  cf* PM  = (cf*)alloc((size_t)POUT*PIN*8);
  cf* M2  = (cf*)alloc((size_t)FRQ*FRQ*8);
  cf* o3b = (cf*)alloc((size_t)FRQ*POUT*8);
  float* bias = (float*)alloc((size_t)SEQ*4);

  fused_pre<<<DOM+1+3072+2048,512,0,stream>>>(WPW,WPb, m1r,m1i,m1br,m1bi, fxr,fxi,fxbr,fxbi,
                                              pjr,pji,pjbr,pjbi, fqWr,fqWi, x, Wpos,
                                              C,PM,M2,o3b, A1r,A1i, Abig);
  p_big3<<<SEQ,512,0,stream>>>(headW, PM, M2, o3b, C, fqbr, fqbi, headb, A1r, A1i, BTm, bias);
  gemm_main<<<dim3(128, 6), 512, 0, stream>>>(BTm, Abig, bias, (float*)d_out);
}